// Round 3
// baseline (221.490 us; speedup 1.0000x reference)
//
#include <hip/hip_runtime.h>
#include <hip/hip_bf16.h>
#include <stdint.h>

#define R_ 8
#define N_ 8192
#define D_ 2048
#define A_ 128
#define J_ 1024          // R_*A_
#define LN_EPS 1e-5f

typedef __attribute__((ext_vector_type(8))) short bf16x8;   // 8 bf16 in 4 VGPRs
typedef __attribute__((ext_vector_type(4))) float f32x4;

__device__ inline ushort f2bf(float f) {
    union { float f; uint32_t u; } v; v.f = f;
    uint32_t u = v.u;
    return (ushort)((u + 0x7fffu + ((u >> 16) & 1u)) >> 16);   // RNE
}
__device__ inline float bf2f(ushort u) {
    union { uint32_t u; float f; } v; v.u = ((uint32_t)u) << 16;
    return v.f;
}

// ---------------------------------------------------------------------------
// k_prep: blocks [0,N_)   : row-LN stats of x -> xhat bf16 (shared by routers)
//         blocks [N_,N_+J_): weight-LN column j -> Bt bf16 (K-major) + cvec
// ---------------------------------------------------------------------------
__global__ __launch_bounds__(256) void k_prep(
    const float* __restrict__ x,
    const float* __restrict__ W,
    const float* __restrict__ ln_w,
    const float* __restrict__ ln_b,
    const float* __restrict__ rw_w,
    const float* __restrict__ rw_b,
    const float* __restrict__ rbias,
    ushort* __restrict__ xhat,
    ushort* __restrict__ Bt,
    float* __restrict__ cvec)
{
    __shared__ float sm[16];
    const int t = threadIdx.x;

    if (blockIdx.x < N_) {
        const int n = blockIdx.x;
        const float* xr = x + (size_t)n * D_;
        float4 v0 = *(const float4*)(xr + t * 4);
        float4 v1 = *(const float4*)(xr + 1024 + t * 4);
        float s  = v0.x + v0.y + v0.z + v0.w + v1.x + v1.y + v1.z + v1.w;
        float sq = v0.x*v0.x + v0.y*v0.y + v0.z*v0.z + v0.w*v0.w
                 + v1.x*v1.x + v1.y*v1.y + v1.z*v1.z + v1.w*v1.w;
        #pragma unroll
        for (int o = 32; o > 0; o >>= 1) {
            s  += __shfl_xor(s,  o, 64);
            sq += __shfl_xor(sq, o, 64);
        }
        if ((t & 63) == 0) { sm[t >> 6] = s; sm[8 + (t >> 6)] = sq; }
        __syncthreads();
        s  = sm[0] + sm[1] + sm[2] + sm[3];
        sq = sm[8] + sm[9] + sm[10] + sm[11];
        const float mean = s * (1.0f / D_);
        const float var  = sq * (1.0f / D_) - mean * mean;
        const float rstd = rsqrtf(var + LN_EPS);

        ushort4 p0 = make_ushort4(f2bf((v0.x - mean) * rstd), f2bf((v0.y - mean) * rstd),
                                  f2bf((v0.z - mean) * rstd), f2bf((v0.w - mean) * rstd));
        ushort4 p1 = make_ushort4(f2bf((v1.x - mean) * rstd), f2bf((v1.y - mean) * rstd),
                                  f2bf((v1.z - mean) * rstd), f2bf((v1.w - mean) * rstd));
        *(ushort4*)(xhat + (size_t)n * D_ + t * 4)        = p0;
        *(ushort4*)(xhat + (size_t)n * D_ + 1024 + t * 4) = p1;
    } else {
        const int j = blockIdx.x - N_;
        const int r = j >> 7, a = j & 127;
        const float* Wc = W + (size_t)r * D_ * A_ + a;

        float vals[8];
        float s = 0.f, sq = 0.f;
        #pragma unroll
        for (int k = 0; k < 8; ++k) {
            float v = Wc[(size_t)(t + k * 256) * A_];
            vals[k] = v; s += v; sq += v * v;
        }
        #pragma unroll
        for (int o = 32; o > 0; o >>= 1) {
            s  += __shfl_xor(s,  o, 64);
            sq += __shfl_xor(sq, o, 64);
        }
        if ((t & 63) == 0) { sm[t >> 6] = s; sm[8 + (t >> 6)] = sq; }
        __syncthreads();
        s  = sm[0] + sm[1] + sm[2] + sm[3];
        sq = sm[8] + sm[9] + sm[10] + sm[11];
        const float mean = s * (1.0f / D_);
        const float var  = sq * (1.0f / D_) - mean * mean;
        const float rstd = rsqrtf(var + LN_EPS);

        float cp = 0.f;
        #pragma unroll
        for (int k = 0; k < 8; ++k) {
            const int d = t + k * 256;
            const float nv = (vals[k] - mean) * rstd * rw_w[(size_t)r * D_ + d]
                           + rw_b[(size_t)r * D_ + d];
            Bt[(size_t)j * D_ + d] = f2bf(ln_w[(size_t)r * D_ + d] * nv);
            cp += ln_b[(size_t)r * D_ + d] * nv;
        }
        __syncthreads();   // sm reuse
        #pragma unroll
        for (int o = 32; o > 0; o >>= 1) cp += __shfl_xor(cp, o, 64);
        if ((t & 63) == 0) sm[t >> 6] = cp;
        __syncthreads();
        if (t == 0) cvec[j] = sm[0] + sm[1] + sm[2] + sm[3] + rbias[(size_t)r * A_ + a];
    }
}

// ---------------------------------------------------------------------------
// k_main: 512 blocks = 64 m-tiles x 8 routers. Block (mt, r):
//   - GEMM logits[r][m0:m0+128][:] = xhat * Bt[r]^T + c, softmax fused
//   - new_x[r][m0:m0+128][:] emitted INSIDE the K-loop from the LDS A-tile
//     (per iter: 128x32 fp32 slab = 16 KiB of the 512 MiB stream -> the write
//     stream paces the loop; MFMA + L2-hot staging hide under it)
// Decode mt = bid&63 keeps all 8 routers of an m-tile on one XCD (bid%8=mt%8).
// ---------------------------------------------------------------------------
__global__ __launch_bounds__(256) void k_main(
    const ushort* __restrict__ Xh,
    const ushort* __restrict__ Bt,
    const float* __restrict__ cvec,
    const float* __restrict__ ln_w,
    const float* __restrict__ ln_b,
    float* __restrict__ new_x,
    float* __restrict__ logits,
    float* __restrict__ probs)
{
    __shared__ __attribute__((aligned(16))) ushort As[128 * 32];
    __shared__ __attribute__((aligned(16))) ushort Bs[128 * 32];
    __shared__ __attribute__((aligned(16))) float lwS[D_];
    __shared__ __attribute__((aligned(16))) float lbS[D_];

    const int t    = threadIdx.x;
    const int lane = t & 63;
    const int w    = t >> 6;                 // wave 0..3
    const int mt   = blockIdx.x & 63;
    const int r    = blockIdx.x >> 6;
    const int m0   = mt * 128;
    const int j0   = r * 128;

    // preload this router's LN params (16 KiB) — covered by first loop barrier
    #pragma unroll
    for (int i = 0; i < 2; ++i) {
        const int idx = t + i * 256;         // 512 float4 chunks each
        ((float4*)lwS)[idx] = ((const float4*)(ln_w + (size_t)r * D_))[idx];
        ((float4*)lbS)[idx] = ((const float4*)(ln_b + (size_t)r * D_))[idx];
    }

    f32x4 acc[2][8];
    #pragma unroll
    for (int mi = 0; mi < 2; ++mi)
        #pragma unroll
        for (int jf = 0; jf < 8; ++jf)
            acc[mi][jf] = (f32x4){0.f, 0.f, 0.f, 0.f};

    float* nx_base = new_x + ((size_t)r * N_ + m0) * D_;

    for (int kt = 0; kt < D_ / 32; ++kt) {
        __syncthreads();                     // prev iter's LDS reads done
        #pragma unroll
        for (int c = 0; c < 2; ++c) {
            const int q   = t + c * 256;     // 16B chunk index 0..511
            const int row = q >> 2;
            const int kc  = q & 3;
            const ushort* gA = Xh + (size_t)(m0 + row) * D_ + kt * 32 + kc * 8;
            __builtin_amdgcn_global_load_lds(
                (const __attribute__((address_space(1))) void*)gA,
                (__attribute__((address_space(3))) void*)(&As[q * 8]), 16, 0, 0);
            const ushort* gB = Bt + (size_t)(j0 + row) * D_ + kt * 32 + kc * 8;
            __builtin_amdgcn_global_load_lds(
                (const __attribute__((address_space(1))) void*)gB,
                (__attribute__((address_space(3))) void*)(&Bs[q * 8]), 16, 0, 0);
        }
        __syncthreads();                     // staging complete

        // ---- new_x slab: 128 rows x 32 cols fp32, 4 chunks/thread ----
        // chunk -> (row, col4); 8 lanes cover one row's 128 B contiguously.
        const int kbase = kt * 32;
        #pragma unroll
        for (int c = 0; c < 4; ++c) {
            const int chunk = t + c * 256;   // 0..1023
            const int row   = chunk >> 3;
            const int col4  = chunk & 7;
            const int d     = kbase + col4 * 4;
            const ushort4 hb = *(const ushort4*)(&As[row * 32 + col4 * 4]);
            const float4 lw4 = *(const float4*)(&lwS[d]);
            const float4 lb4 = *(const float4*)(&lbS[d]);
            float4 o;
            o.x = bf2f(hb.x) * lw4.x + lb4.x;
            o.y = bf2f(hb.y) * lw4.y + lb4.y;
            o.z = bf2f(hb.z) * lw4.z + lb4.z;
            o.w = bf2f(hb.w) * lw4.w + lb4.w;
            *(float4*)(nx_base + (size_t)row * D_ + d) = o;
        }

        // ---- MFMA ----
        bf16x8 afr[2];
        #pragma unroll
        for (int mi = 0; mi < 2; ++mi)
            afr[mi] = *(const bf16x8*)(&As[(w * 32 + mi * 16 + (lane & 15)) * 32
                                           + (lane >> 4) * 8]);
        #pragma unroll
        for (int jf = 0; jf < 8; ++jf) {
            bf16x8 bfr = *(const bf16x8*)(&Bs[(jf * 16 + (lane & 15)) * 32
                                              + (lane >> 4) * 8]);
            acc[0][jf] = __builtin_amdgcn_mfma_f32_16x16x32_bf16(afr[0], bfr, acc[0][jf], 0, 0, 0);
            acc[1][jf] = __builtin_amdgcn_mfma_f32_16x16x32_bf16(afr[1], bfr, acc[1][jf], 0, 0, 0);
        }
    }

    // Epilogue: bias + row softmax (j-tile == router r's full A=128).
    // C/D layout: col = lane&15, row = (lane>>4)*4 + reg.
    float cv[8];
    #pragma unroll
    for (int jf = 0; jf < 8; ++jf) cv[jf] = cvec[j0 + jf * 16 + (lane & 15)];

    #pragma unroll
    for (int mi = 0; mi < 2; ++mi) {
        #pragma unroll
        for (int reg = 0; reg < 4; ++reg) {
            const int row = m0 + w * 32 + mi * 16 + (lane >> 4) * 4 + reg;
            float v[8], e[8];
            float mx = -3.4e38f;
            #pragma unroll
            for (int jf = 0; jf < 8; ++jf) {
                v[jf] = acc[mi][jf][reg] + cv[jf];
                mx = fmaxf(mx, v[jf]);
            }
            #pragma unroll
            for (int o = 8; o > 0; o >>= 1) mx = fmaxf(mx, __shfl_xor(mx, o, 64));
            float ssum = 0.f;
            #pragma unroll
            for (int jf = 0; jf < 8; ++jf) { e[jf] = __expf(v[jf] - mx); ssum += e[jf]; }
            #pragma unroll
            for (int o = 8; o > 0; o >>= 1) ssum += __shfl_xor(ssum, o, 64);
            const float inv = 1.0f / ssum;
            float* lrow = logits + ((size_t)r * N_ + row) * A_;
            float* prow = probs  + ((size_t)r * N_ + row) * A_;
            #pragma unroll
            for (int jf = 0; jf < 8; ++jf) {
                const int aa = jf * 16 + (lane & 15);
                lrow[aa] = v[jf];
                prow[aa] = e[jf] * inv;
            }
        }
    }
}

// ---------------------------------------------------------------------------
extern "C" void kernel_launch(void* const* d_in, const int* in_sizes, int n_in,
                              void* d_out, int out_size, void* d_ws, size_t ws_size,
                              hipStream_t stream)
{
    const float* x     = (const float*)d_in[0];
    const float* ln_w  = (const float*)d_in[1];
    const float* ln_b  = (const float*)d_in[2];
    const float* W     = (const float*)d_in[3];
    const float* rw_w  = (const float*)d_in[4];
    const float* rw_b  = (const float*)d_in[5];
    const float* rbias = (const float*)d_in[6];

    float* out    = (float*)d_out;
    float* new_x  = out;                                   // [R,N,D]
    float* logits = out + (size_t)R_ * N_ * D_;            // [R,N,A]
    float* probs  = logits + (size_t)R_ * N_ * A_;         // [R,N,A]

    // ws: xhat bf16 [N][D] (32 MiB) | Bt bf16 [J][D] (4 MiB) | cvec f32 [J]
    ushort* xhat = (ushort*)d_ws;
    ushort* Btp  = (ushort*)((char*)d_ws + (size_t)N_ * D_ * 2);
    float*  cvec = (float*)((char*)d_ws + (size_t)N_ * D_ * 2 + (size_t)J_ * D_ * 2);

    hipLaunchKernelGGL(k_prep, dim3(N_ + J_), dim3(256), 0, stream,
                       x, W, ln_w, ln_b, rw_w, rw_b, rbias, xhat, Btp, cvec);
    hipLaunchKernelGGL(k_main, dim3(512), dim3(256), 0, stream,
                       xhat, Btp, cvec, ln_w, ln_b, new_x, logits, probs);
}